// Round 1
// 99.182 us; speedup vs baseline: 1.0292x; 1.0292x over previous
//
#include <hip/hip_runtime.h>
#include <math.h>

#define PI_F 3.14159f
#define STRD 69            // row stride: 66 used cols (-1..65 -> slots 0..66) + pad
#define SLICE3 (67 * 69)   // 67 rows (y=-1..65) * stride

typedef float f4 __attribute__((ext_vector_type(4)));  // for nontemporal stores

// One fused kernel: 512 blocks x 256 thr. Block = (b, d-pair), XCD-remapped.
//   1. prefetch 3 z-slices HBM -> regs (in flight during GEMV)
//   2. zero LDS guard rings (2 blended slices)
//   3. p = relu(pc @ W_c + b_c), split-K over 4 waves (overlaps slice drain)
//   4. z-BLEND slices in registers and stage ONE slice per plane:
//        plane0 = (1-wzA)*s[0] + wzA*s[1]
//        plane1 = (1-wzB)*s[slB] + wzB*s[slB+1]
//      Trilinear = bilinear over the z-blended slice (weights separable;
//      zero-padding in z preserved since OOB prefetch slices are zeroed).
//      This halves the per-point LDS gather (8->4 reads) and FMA tree,
//      cuts staged LDS 54.2->37 KB, and removes the mid-kernel slice-2
//      stage + one __syncthreads().
//   5. barrier; heads; barrier
//   6. sample plane 0 (bilinear, 4 taps), NT stores
//   7. sample plane 1, NT stores (no barrier needed between planes)
__global__ __launch_bounds__(256, 2) void adaat_fused_kernel(
    const float* __restrict__ fm,
    const float* __restrict__ para_code,
    const float* __restrict__ W_c, const float* __restrict__ b_c,
    const float* __restrict__ W_s, const float* __restrict__ b_s,
    const float* __restrict__ W_r, const float* __restrict__ b_r,
    const float* __restrict__ W_t, const float* __restrict__ b_t,
    float* __restrict__ out) {
  const int i = blockIdx.x;
  const int bid = ((i & 7) << 6) | (i >> 3);  // XCD-contiguous remap
  const int b = bid >> 7;
  const int d0 = (bid & 127) << 1;
  const int d1 = d0 + 1;
  const int tid = threadIdx.x;

  __shared__ float sm[2 * SLICE3];  // 37.0 KB: one z-blended slice per plane
  __shared__ float redp[4][256];    // GEMV split-K partials
  __shared__ float red[4][8];
  __shared__ float prm[2][5];       // per plane: sc*32*{co,si}, t*32+31.5 folded below

  // ---- z geometry (exact reference formula sequence) ----
  float gz0 = 2.0f * (d0 * (1.0f / 255.0f)) - 1.0f;
  float izA = ((gz0 + 1.0f) * 256.0f - 1.0f) * 0.5f;
  float z0fA = floorf(izA);
  float wzA = izA - z0fA;
  int zA = (int)z0fA;
  float gz1 = 2.0f * (d1 * (1.0f / 255.0f)) - 1.0f;
  float izB = ((gz1 + 1.0f) * 256.0f - 1.0f) * 0.5f;
  float z0fB = floorf(izB);
  float wzB = izB - z0fB;
  int zB = (int)z0fB;
  int slB = zB - zA;  // ==1 for all even d0 (proven); guard anyway
  if (slB > 1) slB = 1;
  if (slB < 0) slB = 0;

  // ---- 1. prefetch 3 slices into registers ----
  float4 pre[3][4];
  const float4* fmb = (const float4*)(fm + ((size_t)b << 20));
#pragma unroll
  for (int s = 0; s < 3; ++s) {
    int z = zA + s;
    if ((unsigned)z < 256u) {  // block-uniform branch
      const float4* src = fmb + ((size_t)z << 10);
#pragma unroll
      for (int k = 0; k < 4; ++k) pre[s][k] = src[(k << 8) + tid];
    } else {
#pragma unroll
      for (int k = 0; k < 4; ++k) pre[s][k] = make_float4(0.f, 0.f, 0.f, 0.f);
    }
  }

  // ---- 2. zero guard rings (no vmcnt dependency) ----
#pragma unroll
  for (int s = 0; s < 2; ++s) {
    float* smb = sm + s * SLICE3;
    if (tid < STRD) {
      smb[tid] = 0.0f;
      smb[65 * STRD + tid] = 0.0f;
      smb[66 * STRD + tid] = 0.0f;
    }
    int r = 1 + (tid >> 2);
    int q = tid & 3;
    int c = q ? (64 + q) : 0;
    smb[r * STRD + c] = 0.0f;
  }

  // ---- 3. GEMV p = relu(pc @ W_c + b_c), split-K over waves ----
  {
    const int wv = tid >> 6, ln = tid & 63;
    const float* pcb = para_code + (b << 8);
    float pcv = pcb[(wv << 6) | ln];
    float4 a4 = make_float4(0.f, 0.f, 0.f, 0.f);
#pragma unroll
    for (int kk = 0; kk < 64; ++kk) {
      float pk = __int_as_float(
          __builtin_amdgcn_readlane(__float_as_int(pcv), kk));
      const float4* Wrow = (const float4*)(W_c + (((wv << 6) + kk) << 8));
      float4 w4 = Wrow[ln];
      a4.x = fmaf(pk, w4.x, a4.x);
      a4.y = fmaf(pk, w4.y, a4.y);
      a4.z = fmaf(pk, w4.z, a4.z);
      a4.w = fmaf(pk, w4.w, a4.w);
    }
    ((float4*)&redp[wv][0])[ln] = a4;
  }

  // ---- 4. z-blend + stage one slice per plane (loads drained under GEMV) ----
  {
    const float wl0 = 1.0f - wzA;
#pragma unroll
    for (int k = 0; k < 4; ++k) {
      int e = ((k << 8) + tid) << 2;
      int y = e >> 6, x0 = e & 63;
      int a = (y + 1) * STRD + x0 + 1;
      float4 v0 = pre[0][k], v1 = pre[1][k];
      sm[a]     = fmaf(wl0, v0.x, wzA * v1.x);
      sm[a + 1] = fmaf(wl0, v0.y, wzA * v1.y);
      sm[a + 2] = fmaf(wl0, v0.z, wzA * v1.z);
      sm[a + 3] = fmaf(wl0, v0.w, wzA * v1.w);
    }
    const float wl1 = 1.0f - wzB;
    float* smb = sm + SLICE3;
    if (slB == 1) {  // block-uniform; the normal case
#pragma unroll
      for (int k = 0; k < 4; ++k) {
        int e = ((k << 8) + tid) << 2;
        int y = e >> 6, x0 = e & 63;
        int a = (y + 1) * STRD + x0 + 1;
        float4 v0 = pre[1][k], v1 = pre[2][k];
        smb[a]     = fmaf(wl1, v0.x, wzB * v1.x);
        smb[a + 1] = fmaf(wl1, v0.y, wzB * v1.y);
        smb[a + 2] = fmaf(wl1, v0.z, wzB * v1.z);
        smb[a + 3] = fmaf(wl1, v0.w, wzB * v1.w);
      }
    } else {
#pragma unroll
      for (int k = 0; k < 4; ++k) {
        int e = ((k << 8) + tid) << 2;
        int y = e >> 6, x0 = e & 63;
        int a = (y + 1) * STRD + x0 + 1;
        float4 v0 = pre[0][k], v1 = pre[1][k];
        smb[a]     = fmaf(wl1, v0.x, wzB * v1.x);
        smb[a + 1] = fmaf(wl1, v0.y, wzB * v1.y);
        smb[a + 2] = fmaf(wl1, v0.z, wzB * v1.z);
        smb[a + 3] = fmaf(wl1, v0.w, wzB * v1.w);
      }
    }
  }
  __syncthreads();  // covers both blended slices and redp

  // ---- 5. heads: 8 dot-products (2 planes x {s,r,t0,t1}) ----
  {
    float pk = fmaxf(redp[0][tid] + redp[1][tid] + redp[2][tid] +
                         redp[3][tid] + b_c[tid],
                     0.0f);
    float2 ws = *(const float2*)(W_s + (tid << 8) + d0);
    float2 wr = *(const float2*)(W_r + (tid << 8) + d0);
    float4 wt = *(const float4*)(W_t + (tid << 9) + (d0 << 1));
    float v0 = pk * ws.x, v1 = pk * ws.y;
    float v2 = pk * wr.x, v3 = pk * wr.y;
    float v4 = pk * wt.x, v5 = pk * wt.z;
    float v6 = pk * wt.y, v7 = pk * wt.w;
#pragma unroll
    for (int off = 32; off > 0; off >>= 1) {
      v0 += __shfl_xor(v0, off);
      v1 += __shfl_xor(v1, off);
      v2 += __shfl_xor(v2, off);
      v3 += __shfl_xor(v3, off);
      v4 += __shfl_xor(v4, off);
      v5 += __shfl_xor(v5, off);
      v6 += __shfl_xor(v6, off);
      v7 += __shfl_xor(v7, off);
    }
    int wv = tid >> 6;
    if ((tid & 63) == 0) {
      red[wv][0] = v0; red[wv][1] = v1; red[wv][2] = v2; red[wv][3] = v3;
      red[wv][4] = v4; red[wv][5] = v5; red[wv][6] = v6; red[wv][7] = v7;
    }
  }
  __syncthreads();
  if (tid < 8) {
    float v = red[0][tid] + red[1][tid] + red[2][tid] + red[3][tid];
    int pl = tid & 1;
    int dsel = d0 + pl;
    int typ = tid >> 1;  // 0:scale 1:rot 2:t0 3:t1
    if (typ == 0) {
      v += b_s[dsel];
      prm[pl][0] = 2.0f / (1.0f + expf(-v));
    } else if (typ == 1) {
      v += b_r[dsel];
      float ang = tanhf(v) * PI_F;
      prm[pl][1] = cosf(ang);
      prm[pl][2] = sinf(ang);
    } else if (typ == 2) {
      v += b_t[2 * dsel];
      prm[pl][3] = tanhf(v);
    } else {
      v += b_t[2 * dsel + 1];
      prm[pl][4] = tanhf(v);
    }
  }
  __syncthreads();

  // ---- 6/7. sample plane 0 then plane 1 (bilinear on blended slice) ----
  const float dgx = 2.0f / 63.0f;
  const int w0 = (tid & 15) << 2;
  const int h0 = tid >> 4;
  const float gx0 = w0 * dgx - 1.0f;

#pragma unroll
  for (int pl = 0; pl < 2; ++pl) {
    const float sc = prm[pl][0];
    const float co = prm[pl][1];
    const float si = prm[pl][2];
    const float t0 = prm[pl][3];
    const float t1 = prm[pl][4];
    const float* smA = sm + pl * SLICE3;
    float* outp = out + (((size_t)(b << 8) + d0 + pl) << 12);

    const float co32 = co * sc * 32.0f;
    const float si32 = si * sc * 32.0f;
    const float stx = co32 * dgx;
    const float sty = si32 * dgx;
    const float ixw = fmaf(co32, gx0, fmaf(t0, 32.0f, 31.5f));
    const float iyw = fmaf(si32, gx0, fmaf(t1, 32.0f, 31.5f));

#pragma unroll
    for (int j = 0; j < 4; ++j) {
      int h = (j << 4) + h0;
      float gy = h * dgx - 1.0f;
      float ix = fmaf(-si32, gy, ixw);
      float iy = fmaf(co32, gy, iyw);
      float rr[4];
#pragma unroll
      for (int q = 0; q < 4; ++q) {
        float x0f = floorf(ix), y0f = floorf(iy);
        float wx = ix - x0f, wy = iy - y0f;
        int xi = (int)x0f, yi = (int)y0f;
        int bx = min(max(xi, -1), 64);  // v_med3_i32
        int by = min(max(yi, -1), 64);
        float wxe = (bx == xi) ? wx : 0.0f;
        float wye = (by == yi) ? wy : 0.0f;
        float w11 = wye * wxe;
        float w10 = wye - w11;
        float w01 = wxe - w11;
        float w00 = (1.0f - wye) - w01;
        int base = (by + 1) * STRD + bx + 1;
        rr[q] = fmaf(smA[base], w00,
                fmaf(smA[base + 1], w01,
                fmaf(smA[base + STRD], w10, smA[base + STRD + 1] * w11)));
        ix += stx;
        iy += sty;
      }
      f4 res;
      res.x = rr[0]; res.y = rr[1]; res.z = rr[2]; res.w = rr[3];
      __builtin_nontemporal_store(res, (f4*)outp + (j << 8) + tid);
    }
  }
}

extern "C" void kernel_launch(void* const* d_in, const int* in_sizes, int n_in,
                              void* d_out, int out_size, void* d_ws, size_t ws_size,
                              hipStream_t stream) {
  const float* fm        = (const float*)d_in[0];  // (4,256,64,64)
  const float* para_code = (const float*)d_in[1];  // (4,256)
  const float* W_c       = (const float*)d_in[2];  // (256,256)
  const float* b_c       = (const float*)d_in[3];  // (256,)
  const float* W_s       = (const float*)d_in[4];  // (256,256)
  const float* b_s       = (const float*)d_in[5];  // (256,)
  const float* W_r       = (const float*)d_in[6];  // (256,256)
  const float* b_r       = (const float*)d_in[7];  // (256,)
  const float* W_t       = (const float*)d_in[8];  // (256,512)
  const float* b_t       = (const float*)d_in[9];  // (512,)
  float* out = (float*)d_out;

  adaat_fused_kernel<<<512, 256, 0, stream>>>(
      fm, para_code, W_c, b_c, W_s, b_s, W_r, b_r, W_t, b_t, out);
}

// Round 2
// 97.960 us; speedup vs baseline: 1.0420x; 1.0125x over previous
//
#include <hip/hip_runtime.h>
#include <math.h>

#define PI_F 3.14159f
#define STRD 69            // row stride: 66 used cols (-1..65 -> slots 0..66) + pad
#define SLICE3 (67 * 69)   // 67 rows (y=-1..65) * stride

typedef float f4 __attribute__((ext_vector_type(4)));  // for nontemporal stores

// One fused kernel: 256 blocks x 512 thr. Block = (b, 4 consecutive d), XCD-remapped.
// Halves W_c L2 traffic vs 512-block version (each block reads the full 256KB
// W_c once; fewer blocks => less redundant GEMV).
//   1. prefetch 5(+1 guard) z-slices HBM -> regs (in flight during GEMV)
//   2. zero LDS guard rings (4 blended slices)
//   3. p = relu(pc @ W_c + b_c), split-K over 8 waves (overlaps slice drain)
//   4. z-BLEND slices in registers, stage ONE slice per plane (4 planes)
//   5. barrier; heads (two 256-thread groups, one d-pair each); barrier
//   6. sample 2 planes per group (bilinear, 4 taps), NT stores
__global__ __launch_bounds__(512, 2) void adaat_fused_kernel(
    const float* __restrict__ fm,
    const float* __restrict__ para_code,
    const float* __restrict__ W_c, const float* __restrict__ b_c,
    const float* __restrict__ W_s, const float* __restrict__ b_s,
    const float* __restrict__ W_r, const float* __restrict__ b_r,
    const float* __restrict__ W_t, const float* __restrict__ b_t,
    float* __restrict__ out) {
  const int i = blockIdx.x;
  const int bid = ((i & 7) << 5) | (i >> 3);  // XCD-contiguous remap (256 blocks)
  const int b = bid >> 6;
  const int dbase = (bid & 63) << 2;  // 4 consecutive d values
  const int tid = threadIdx.x;

  __shared__ float sm[4 * SLICE3];  // 74.0 KB: one z-blended slice per plane
  __shared__ float redp[8][256];    // GEMV split-K partials (8 waves)
  __shared__ float red[8][8];
  __shared__ float prm[4][5];       // per plane: sc,co,si,t0,t1

  // ---- z geometry (exact reference formula sequence, per plane) ----
  float wz[4];
  int z0i[4];
#pragma unroll
  for (int j = 0; j < 4; ++j) {
    float gz = 2.0f * ((dbase + j) * (1.0f / 255.0f)) - 1.0f;
    float iz = ((gz + 1.0f) * 256.0f - 1.0f) * 0.5f;
    float z0f = floorf(iz);
    wz[j] = iz - z0f;
    z0i[j] = (int)z0f;
  }
  const int zbase = z0i[0];
  int sl3 = z0i[3] - zbase;  // 3 in exact math; guard 4 for f32 rounding
  if (sl3 < 3) sl3 = 3;
  if (sl3 > 4) sl3 = 4;

  // ---- 1. prefetch up to 6 slices into registers (2 float4 per thread each) --
  float4 pre[6][2];
  const float4* fmb = (const float4*)(fm + ((size_t)b << 20));
#pragma unroll
  for (int s = 0; s < 6; ++s) {
    int z = zbase + s;
    bool need = (s < 5) || (sl3 == 4);  // block-uniform
    if (need && (unsigned)z < 256u) {   // block-uniform branch
      const float4* src = fmb + ((size_t)z << 10);
      pre[s][0] = src[tid];
      pre[s][1] = src[512 + tid];
    } else {
      pre[s][0] = make_float4(0.f, 0.f, 0.f, 0.f);
      pre[s][1] = make_float4(0.f, 0.f, 0.f, 0.f);
    }
  }

  // ---- 2. zero guard rings (no vmcnt dependency) ----
  {
    int s2 = tid >> 8;  // 0/1 -> slices {s2, s2+2}
    int t = tid & 255;
#pragma unroll
    for (int ss = 0; ss < 2; ++ss) {
      float* smb = sm + (s2 + (ss << 1)) * SLICE3;
      if (t < STRD) {
        smb[t] = 0.0f;
        smb[65 * STRD + t] = 0.0f;
        smb[66 * STRD + t] = 0.0f;
      }
      int r = 1 + (t >> 2);
      int q = t & 3;
      int c = q ? (64 + q) : 0;
      smb[r * STRD + c] = 0.0f;
    }
  }

  // ---- 3. GEMV p = relu(pc @ W_c + b_c), split-K over 8 waves ----
  {
    const int wv = tid >> 6, ln = tid & 63;
    const float* pcb = para_code + (b << 8);
    float pcv = pcb[(wv << 5) | (ln & 31)];
    float4 a4 = make_float4(0.f, 0.f, 0.f, 0.f);
#pragma unroll
    for (int kk = 0; kk < 32; ++kk) {
      float pk = __int_as_float(
          __builtin_amdgcn_readlane(__float_as_int(pcv), kk));
      const float4* Wrow = (const float4*)(W_c + (((wv << 5) + kk) << 8));
      float4 w4 = Wrow[ln];
      a4.x = fmaf(pk, w4.x, a4.x);
      a4.y = fmaf(pk, w4.y, a4.y);
      a4.z = fmaf(pk, w4.z, a4.z);
      a4.w = fmaf(pk, w4.w, a4.w);
    }
    ((float4*)&redp[wv][0])[ln] = a4;
  }

  // ---- 4. z-blend + stage one slice per plane (loads drained under GEMV) ----
#pragma unroll
  for (int j = 0; j < 4; ++j) {
    const float wh = wz[j];
    const float wl = 1.0f - wh;
    float* smb = sm + j * SLICE3;
    int slj = z0i[j] - zbase;       // == j in exact math; {j, j+1} guarded
    const bool hi = (slj > j);      // block-uniform
#pragma unroll
    for (int k = 0; k < 2; ++k) {
      int e = ((k << 9) + tid) << 2;
      int y = e >> 6, x0 = e & 63;
      int a = (y + 1) * STRD + x0 + 1;
      float4 v0, v1;
      if (hi) {
        v0 = pre[j + 1][k];
        v1 = pre[j + 2][k];
      } else {
        v0 = pre[j][k];
        v1 = pre[j + 1][k];
      }
      smb[a]     = fmaf(wl, v0.x, wh * v1.x);
      smb[a + 1] = fmaf(wl, v0.y, wh * v1.y);
      smb[a + 2] = fmaf(wl, v0.z, wh * v1.z);
      smb[a + 3] = fmaf(wl, v0.w, wh * v1.w);
    }
  }
  __syncthreads();  // covers all 4 blended slices and redp

  // ---- 5. heads: two 256-thread groups, 8 dot-products each ----
  {
    int t = tid & 255;
    int g = tid >> 8;                 // group 0/1 -> d-pair (dbase+2g, +1)
    int d0g = dbase + (g << 1);
    float pk = redp[0][t] + redp[1][t] + redp[2][t] + redp[3][t] +
               redp[4][t] + redp[5][t] + redp[6][t] + redp[7][t] + b_c[t];
    pk = fmaxf(pk, 0.0f);
    float2 ws = *(const float2*)(W_s + (t << 8) + d0g);
    float2 wr = *(const float2*)(W_r + (t << 8) + d0g);
    float4 wt = *(const float4*)(W_t + (t << 9) + (d0g << 1));
    float v0 = pk * ws.x, v1 = pk * ws.y;
    float v2 = pk * wr.x, v3 = pk * wr.y;
    float v4 = pk * wt.x, v5 = pk * wt.z;
    float v6 = pk * wt.y, v7 = pk * wt.w;
#pragma unroll
    for (int off = 32; off > 0; off >>= 1) {
      v0 += __shfl_xor(v0, off);
      v1 += __shfl_xor(v1, off);
      v2 += __shfl_xor(v2, off);
      v3 += __shfl_xor(v3, off);
      v4 += __shfl_xor(v4, off);
      v5 += __shfl_xor(v5, off);
      v6 += __shfl_xor(v6, off);
      v7 += __shfl_xor(v7, off);
    }
    int wv = tid >> 6;
    if ((tid & 63) == 0) {
      red[wv][0] = v0; red[wv][1] = v1; red[wv][2] = v2; red[wv][3] = v3;
      red[wv][4] = v4; red[wv][5] = v5; red[wv][6] = v6; red[wv][7] = v7;
    }
  }
  __syncthreads();
  if (tid < 16) {
    int g = tid >> 3, j = tid & 7;
    int wb = g << 2;  // group g's waves are wb..wb+3
    float v = red[wb][j] + red[wb + 1][j] + red[wb + 2][j] + red[wb + 3][j];
    int pl = j & 1;
    int plane = (g << 1) + pl;
    int dsel = dbase + plane;
    int typ = j >> 1;  // 0:scale 1:rot 2:t0 3:t1
    if (typ == 0) {
      v += b_s[dsel];
      prm[plane][0] = 2.0f / (1.0f + expf(-v));
    } else if (typ == 1) {
      v += b_r[dsel];
      float ang = tanhf(v) * PI_F;
      prm[plane][1] = cosf(ang);
      prm[plane][2] = sinf(ang);
    } else if (typ == 2) {
      v += b_t[2 * dsel];
      prm[plane][3] = tanhf(v);
    } else {
      v += b_t[2 * dsel + 1];
      prm[plane][4] = tanhf(v);
    }
  }
  __syncthreads();

  // ---- 6. sample: each 256-thread group does its 2 planes (bilinear) ----
  const float dgx = 2.0f / 63.0f;
  const int t = tid & 255;
  const int g = tid >> 8;
  const int w0 = (t & 15) << 2;
  const int h0 = t >> 4;
  const float gx0 = w0 * dgx - 1.0f;

#pragma unroll
  for (int pq = 0; pq < 2; ++pq) {
    const int plane = (g << 1) + pq;
    const float sc = prm[plane][0];
    const float co = prm[plane][1];
    const float si = prm[plane][2];
    const float t0 = prm[plane][3];
    const float t1 = prm[plane][4];
    const float* smA = sm + plane * SLICE3;
    float* outp = out + (((size_t)(b << 8) + dbase + plane) << 12);

    const float co32 = co * sc * 32.0f;
    const float si32 = si * sc * 32.0f;
    const float stx = co32 * dgx;
    const float sty = si32 * dgx;
    const float ixw = fmaf(co32, gx0, fmaf(t0, 32.0f, 31.5f));
    const float iyw = fmaf(si32, gx0, fmaf(t1, 32.0f, 31.5f));

#pragma unroll
    for (int j = 0; j < 4; ++j) {
      int h = (j << 4) + h0;
      float gy = h * dgx - 1.0f;
      float ix = fmaf(-si32, gy, ixw);
      float iy = fmaf(co32, gy, iyw);
      float rr[4];
#pragma unroll
      for (int q = 0; q < 4; ++q) {
        float x0f = floorf(ix), y0f = floorf(iy);
        float wx = ix - x0f, wy = iy - y0f;
        int xi = (int)x0f, yi = (int)y0f;
        int bx = min(max(xi, -1), 64);  // v_med3_i32
        int by = min(max(yi, -1), 64);
        float wxe = (bx == xi) ? wx : 0.0f;
        float wye = (by == yi) ? wy : 0.0f;
        float w11 = wye * wxe;
        float w10 = wye - w11;
        float w01 = wxe - w11;
        float w00 = (1.0f - wye) - w01;
        int base = (by + 1) * STRD + bx + 1;
        rr[q] = fmaf(smA[base], w00,
                fmaf(smA[base + 1], w01,
                fmaf(smA[base + STRD], w10, smA[base + STRD + 1] * w11)));
        ix += stx;
        iy += sty;
      }
      f4 res;
      res.x = rr[0]; res.y = rr[1]; res.z = rr[2]; res.w = rr[3];
      __builtin_nontemporal_store(res, (f4*)outp + (j << 8) + t);
    }
  }
}

extern "C" void kernel_launch(void* const* d_in, const int* in_sizes, int n_in,
                              void* d_out, int out_size, void* d_ws, size_t ws_size,
                              hipStream_t stream) {
  const float* fm        = (const float*)d_in[0];  // (4,256,64,64)
  const float* para_code = (const float*)d_in[1];  // (4,256)
  const float* W_c       = (const float*)d_in[2];  // (256,256)
  const float* b_c       = (const float*)d_in[3];  // (256,)
  const float* W_s       = (const float*)d_in[4];  // (256,256)
  const float* b_s       = (const float*)d_in[5];  // (256,)
  const float* W_r       = (const float*)d_in[6];  // (256,256)
  const float* b_r       = (const float*)d_in[7];  // (256,)
  const float* W_t       = (const float*)d_in[8];  // (256,512)
  const float* b_t       = (const float*)d_in[9];  // (512,)
  float* out = (float*)d_out;

  adaat_fused_kernel<<<256, 512, 0, stream>>>(
      fm, para_code, W_c, b_c, W_s, b_s, W_r, b_r, W_t, b_t, out);
}

// Round 3
// 97.353 us; speedup vs baseline: 1.0485x; 1.0062x over previous
//
#include <hip/hip_runtime.h>
#include <math.h>

#define PI_F 3.14159f
#define STRD 69            // row stride: 66 used cols (-1..65 -> slots 0..66) + pad
#define SLICE3 (67 * 69)   // 67 rows (y=-1..65) * stride

typedef float f4 __attribute__((ext_vector_type(4)));  // for nontemporal stores

// One fused kernel: 256 blocks x 512 thr. Block = (b, 4 consecutive d), XCD-remapped.
// WAVE SPECIALIZATION: vmcnt is a per-wave FIFO, so mixing HBM prefetch and L2
// GEMV loads in one wave serializes them (waiting on a GEMV load drains all
// older prefetch loads). Split:
//   waves 4-7: prefetch 5(+1 guard) z-slices HBM->regs, z-BLEND, stage 4
//              plane-slices to LDS (their vmcnt queue holds only fm loads)
//   waves 0-3: zero guard rings, then GEMV p = relu(pc@W_c+b_c) split-K
//              (their vmcnt queue holds only W_c L2 loads)
//   barrier; heads (two 256-thr groups, one d-pair each); barrier;
//   sample 2 planes per group (bilinear on z-blended slice), NT stores.
__global__ __launch_bounds__(512, 2) void adaat_fused_kernel(
    const float* __restrict__ fm,
    const float* __restrict__ para_code,
    const float* __restrict__ W_c, const float* __restrict__ b_c,
    const float* __restrict__ W_s, const float* __restrict__ b_s,
    const float* __restrict__ W_r, const float* __restrict__ b_r,
    const float* __restrict__ W_t, const float* __restrict__ b_t,
    float* __restrict__ out) {
  const int i = blockIdx.x;
  const int bid = ((i & 7) << 5) | (i >> 3);  // XCD-contiguous remap (256 blocks)
  const int b = bid >> 6;
  const int dbase = (bid & 63) << 2;  // 4 consecutive d values
  const int tid = threadIdx.x;

  __shared__ float sm[4 * SLICE3];  // 74.0 KB: one z-blended slice per plane
  __shared__ float redp[4][256];    // GEMV split-K partials (4 waves) - 4 KB
  __shared__ float red[8][8];
  __shared__ float prm[4][5];       // per plane: sc,co,si,t0,t1

  // ---- z geometry (exact reference formula sequence, per plane) ----
  float wz[4];
  int z0i[4];
#pragma unroll
  for (int j = 0; j < 4; ++j) {
    float gz = 2.0f * ((dbase + j) * (1.0f / 255.0f)) - 1.0f;
    float iz = ((gz + 1.0f) * 256.0f - 1.0f) * 0.5f;
    float z0f = floorf(iz);
    wz[j] = iz - z0f;
    z0i[j] = (int)z0f;
  }
  const int zbase = z0i[0];
  int sl3 = z0i[3] - zbase;  // 3 in exact math; guard 4 for f32 rounding
  if (sl3 < 3) sl3 = 3;
  if (sl3 > 4) sl3 = 4;

  if (tid >= 256) {
    // ================= waves 4-7: prefetch + blend + stage =================
    const int t = tid & 255;
    // prefetch up to 6 slices (4 float4 per thread each; 16KB slice / 256 thr)
    float4 pre[6][4];
    const float4* fmb = (const float4*)(fm + ((size_t)b << 20));
#pragma unroll
    for (int s = 0; s < 6; ++s) {
      int z = zbase + s;
      bool need = (s < 5) || (sl3 == 4);  // block-uniform
      if (need && (unsigned)z < 256u) {   // block-uniform branch
        const float4* src = fmb + ((size_t)z << 10);
#pragma unroll
        for (int k = 0; k < 4; ++k) pre[s][k] = src[(k << 8) + t];
      } else {
#pragma unroll
        for (int k = 0; k < 4; ++k) pre[s][k] = make_float4(0.f, 0.f, 0.f, 0.f);
      }
    }
    // z-blend + stage one slice per plane
#pragma unroll
    for (int j = 0; j < 4; ++j) {
      const float wh = wz[j];
      const float wl = 1.0f - wh;
      float* smb = sm + j * SLICE3;
      int slj = z0i[j] - zbase;       // == j in exact math; {j, j+1} guarded
      const bool hi = (slj > j);      // block-uniform
#pragma unroll
      for (int k = 0; k < 4; ++k) {
        int e = ((k << 8) + t) << 2;
        int y = e >> 6, x0 = e & 63;
        int a = (y + 1) * STRD + x0 + 1;
        float4 v0, v1;
        if (hi) {
          v0 = pre[j + 1][k];
          v1 = pre[j + 2][k];
        } else {
          v0 = pre[j][k];
          v1 = pre[j + 1][k];
        }
        smb[a]     = fmaf(wl, v0.x, wh * v1.x);
        smb[a + 1] = fmaf(wl, v0.y, wh * v1.y);
        smb[a + 2] = fmaf(wl, v0.z, wh * v1.z);
        smb[a + 3] = fmaf(wl, v0.w, wh * v1.w);
      }
    }
  } else {
    // ================= waves 0-3: guard rings + GEMV =================
    const int t = tid;
    // zero guard rings for all 4 blended slices (no vmcnt dependency)
#pragma unroll
    for (int ss = 0; ss < 4; ++ss) {
      float* smb = sm + ss * SLICE3;
      if (t < STRD) {
        smb[t] = 0.0f;
        smb[65 * STRD + t] = 0.0f;
        smb[66 * STRD + t] = 0.0f;
      }
      int r = 1 + (t >> 2);
      int q = t & 3;
      int c = q ? (64 + q) : 0;
      smb[r * STRD + c] = 0.0f;
    }
    // GEMV p = relu(pc @ W_c + b_c), split-K over 4 waves (k=64 each)
    const int wv = t >> 6, ln = t & 63;
    const float* pcb = para_code + (b << 8);
    float pcv = pcb[(wv << 6) | ln];
    float4 a4 = make_float4(0.f, 0.f, 0.f, 0.f);
#pragma unroll
    for (int kk = 0; kk < 64; ++kk) {
      float pk = __int_as_float(
          __builtin_amdgcn_readlane(__float_as_int(pcv), kk));
      const float4* Wrow = (const float4*)(W_c + (((wv << 6) + kk) << 8));
      float4 w4 = Wrow[ln];
      a4.x = fmaf(pk, w4.x, a4.x);
      a4.y = fmaf(pk, w4.y, a4.y);
      a4.z = fmaf(pk, w4.z, a4.z);
      a4.w = fmaf(pk, w4.w, a4.w);
    }
    ((float4*)&redp[wv][0])[ln] = a4;
  }
  __syncthreads();  // covers all 4 blended slices and redp

  // ---- heads: two 256-thread groups, 8 dot-products each ----
  {
    int t = tid & 255;
    int g = tid >> 8;                 // group 0/1 -> d-pair (dbase+2g, +1)
    int d0g = dbase + (g << 1);
    float pk = redp[0][t] + redp[1][t] + redp[2][t] + redp[3][t] + b_c[t];
    pk = fmaxf(pk, 0.0f);
    float2 ws = *(const float2*)(W_s + (t << 8) + d0g);
    float2 wr = *(const float2*)(W_r + (t << 8) + d0g);
    float4 wt = *(const float4*)(W_t + (t << 9) + (d0g << 1));
    float v0 = pk * ws.x, v1 = pk * ws.y;
    float v2 = pk * wr.x, v3 = pk * wr.y;
    float v4 = pk * wt.x, v5 = pk * wt.z;
    float v6 = pk * wt.y, v7 = pk * wt.w;
#pragma unroll
    for (int off = 32; off > 0; off >>= 1) {
      v0 += __shfl_xor(v0, off);
      v1 += __shfl_xor(v1, off);
      v2 += __shfl_xor(v2, off);
      v3 += __shfl_xor(v3, off);
      v4 += __shfl_xor(v4, off);
      v5 += __shfl_xor(v5, off);
      v6 += __shfl_xor(v6, off);
      v7 += __shfl_xor(v7, off);
    }
    int wv = tid >> 6;
    if ((tid & 63) == 0) {
      red[wv][0] = v0; red[wv][1] = v1; red[wv][2] = v2; red[wv][3] = v3;
      red[wv][4] = v4; red[wv][5] = v5; red[wv][6] = v6; red[wv][7] = v7;
    }
  }
  __syncthreads();
  if (tid < 16) {
    int g = tid >> 3, j = tid & 7;
    int wb = g << 2;  // group g's waves are wb..wb+3
    float v = red[wb][j] + red[wb + 1][j] + red[wb + 2][j] + red[wb + 3][j];
    int pl = j & 1;
    int plane = (g << 1) + pl;
    int dsel = dbase + plane;
    int typ = j >> 1;  // 0:scale 1:rot 2:t0 3:t1
    if (typ == 0) {
      v += b_s[dsel];
      prm[plane][0] = 2.0f / (1.0f + expf(-v));
    } else if (typ == 1) {
      v += b_r[dsel];
      float ang = tanhf(v) * PI_F;
      prm[plane][1] = cosf(ang);
      prm[plane][2] = sinf(ang);
    } else if (typ == 2) {
      v += b_t[2 * dsel];
      prm[plane][3] = tanhf(v);
    } else {
      v += b_t[2 * dsel + 1];
      prm[plane][4] = tanhf(v);
    }
  }
  __syncthreads();

  // ---- sample: each 256-thread group does its 2 planes (bilinear) ----
  const float dgx = 2.0f / 63.0f;
  const int t = tid & 255;
  const int g = tid >> 8;
  const int w0 = (t & 15) << 2;
  const int h0 = t >> 4;
  const float gx0 = w0 * dgx - 1.0f;

#pragma unroll
  for (int pq = 0; pq < 2; ++pq) {
    const int plane = (g << 1) + pq;
    const float sc = prm[plane][0];
    const float co = prm[plane][1];
    const float si = prm[plane][2];
    const float t0 = prm[plane][3];
    const float t1 = prm[plane][4];
    const float* smA = sm + plane * SLICE3;
    float* outp = out + (((size_t)(b << 8) + dbase + plane) << 12);

    const float co32 = co * sc * 32.0f;
    const float si32 = si * sc * 32.0f;
    const float stx = co32 * dgx;
    const float sty = si32 * dgx;
    const float ixw = fmaf(co32, gx0, fmaf(t0, 32.0f, 31.5f));
    const float iyw = fmaf(si32, gx0, fmaf(t1, 32.0f, 31.5f));

#pragma unroll
    for (int j = 0; j < 4; ++j) {
      int h = (j << 4) + h0;
      float gy = h * dgx - 1.0f;
      float ix = fmaf(-si32, gy, ixw);
      float iy = fmaf(co32, gy, iyw);
      float rr[4];
#pragma unroll
      for (int q = 0; q < 4; ++q) {
        float x0f = floorf(ix), y0f = floorf(iy);
        float wx = ix - x0f, wy = iy - y0f;
        int xi = (int)x0f, yi = (int)y0f;
        int bx = min(max(xi, -1), 64);  // v_med3_i32
        int by = min(max(yi, -1), 64);
        float wxe = (bx == xi) ? wx : 0.0f;
        float wye = (by == yi) ? wy : 0.0f;
        float w11 = wye * wxe;
        float w10 = wye - w11;
        float w01 = wxe - w11;
        float w00 = (1.0f - wye) - w01;
        int base = (by + 1) * STRD + bx + 1;
        rr[q] = fmaf(smA[base], w00,
                fmaf(smA[base + 1], w01,
                fmaf(smA[base + STRD], w10, smA[base + STRD + 1] * w11)));
        ix += stx;
        iy += sty;
      }
      f4 res;
      res.x = rr[0]; res.y = rr[1]; res.z = rr[2]; res.w = rr[3];
      __builtin_nontemporal_store(res, (f4*)outp + (j << 8) + t);
    }
  }
}

extern "C" void kernel_launch(void* const* d_in, const int* in_sizes, int n_in,
                              void* d_out, int out_size, void* d_ws, size_t ws_size,
                              hipStream_t stream) {
  const float* fm        = (const float*)d_in[0];  // (4,256,64,64)
  const float* para_code = (const float*)d_in[1];  // (4,256)
  const float* W_c       = (const float*)d_in[2];  // (256,256)
  const float* b_c       = (const float*)d_in[3];  // (256,)
  const float* W_s       = (const float*)d_in[4];  // (256,256)
  const float* b_s       = (const float*)d_in[5];  // (256,)
  const float* W_r       = (const float*)d_in[6];  // (256,256)
  const float* b_r       = (const float*)d_in[7];  // (256,)
  const float* W_t       = (const float*)d_in[8];  // (256,512)
  const float* b_t       = (const float*)d_in[9];  // (512,)
  float* out = (float*)d_out;

  adaat_fused_kernel<<<256, 512, 0, stream>>>(
      fm, para_code, W_c, b_c, W_s, b_s, W_r, b_r, W_t, b_t, out);
}

// Round 4
// 96.888 us; speedup vs baseline: 1.0536x; 1.0048x over previous
//
#include <hip/hip_runtime.h>
#include <math.h>

#define PI_F 3.14159f
#define STRD 69            // row stride: 66 used cols (-1..65 -> slots 0..66) + pad
#define SLICE3 (67 * 69)   // 67 rows (y=-1..65) * stride

typedef float f4 __attribute__((ext_vector_type(4)));  // for nontemporal stores

// Fused kernel: 256 blocks x 512 thr. Block = (b, 4 consecutive d), XCD-remapped.
// PIPELINED: planes 0/1 need only slices 0-2 (48 KB of the 80 KB prefetch), so
// sampling of planes 0/1 starts as soon as those drain (~2 us) while slices 3/4
// finish in the loader waves' vmcnt queue; planes 2/3 are staged behind the
// plane-1 sampling and sampled last. NT-store drain starts ~1.2 us earlier.
//   waves 4-7 (loader):  issue 5(+1) slice loads | B0 | stage planes 0,1 | B1 |
//                        B2 | sample plane 1; stage planes 2,3 | B3 | sample 3
//   waves 0-3 (compute): rings+W-prefetch+GEMV   | B0 | heads part1      | B1 |
//                        part2(tid<16) | B2 | sample plane 0 | B3 | sample 2
// Heads math is bit-identical to the 2-group version: same per-thread fma, same
// 64-lane shfl tree over t&63, same red[0..3] partial-sum order per output.
__global__ __launch_bounds__(512, 2) void adaat_fused_kernel(
    const float* __restrict__ fm,
    const float* __restrict__ para_code,
    const float* __restrict__ W_c, const float* __restrict__ b_c,
    const float* __restrict__ W_s, const float* __restrict__ b_s,
    const float* __restrict__ W_r, const float* __restrict__ b_r,
    const float* __restrict__ W_t, const float* __restrict__ b_t,
    float* __restrict__ out) {
  const int i = blockIdx.x;
  const int bid = ((i & 7) << 5) | (i >> 3);  // XCD-contiguous remap (256 blocks)
  const int b = bid >> 6;
  const int dbase = (bid & 63) << 2;  // 4 consecutive d values
  const int tid = threadIdx.x;
  const int t = tid & 255;

  __shared__ __align__(16) float sm[4 * SLICE3];  // 74.0 KB blended slices
  __shared__ __align__(16) float redp[4][256];    // GEMV split-K partials
  __shared__ __align__(16) float red[4][16];      // head partials (4 waves x 16 dots)
  __shared__ float prm[4][5];                     // per plane: sc,co,si,t0,t1

  // ---- z geometry (exact reference formula sequence, per plane) ----
  float wz[4];
  int z0i[4];
#pragma unroll
  for (int j = 0; j < 4; ++j) {
    float gz = 2.0f * ((dbase + j) * (1.0f / 255.0f)) - 1.0f;
    float iz = ((gz + 1.0f) * 256.0f - 1.0f) * 0.5f;
    float z0f = floorf(iz);
    wz[j] = iz - z0f;
    z0i[j] = (int)z0f;
  }
  const int zbase = z0i[0];
  // fast == (z0 steps are exactly 1,1,1 within the block) — true for all blocks
  // in exact math (the double-step sits on the d=127->128 block boundary);
  // guarded against f32 rounding. Block-uniform.
  const bool fast = (z0i[1] - zbase == 1) && (z0i[2] - zbase == 2) &&
                    (z0i[3] - zbase == 3);

  // persists across barrier regions (loader waves only)
  float4 pre[6][4];
  // persists for compute waves (heads part1 inputs, issued before GEMV)
  float4 ws4, wr4, wt0, wt1;
  float bcv = 0.0f, bias16 = 0.0f;

  // z-blend + stage plane J from pre[] into sm (loader waves, t in 0..255).
  // Compile-time J keeps all pre[] indices constant (no scratch).
#define STAGE(J)                                                         \
  do {                                                                   \
    const float wh = wz[(J)];                                            \
    const float wl = 1.0f - wh;                                          \
    float* smb = sm + (J)*SLICE3;                                        \
    const bool hi = (z0i[(J)] - zbase) > (J); /* block-uniform */        \
    _Pragma("unroll") for (int k = 0; k < 4; ++k) {                      \
      int e = ((k << 8) + t) << 2;                                       \
      int y = e >> 6, x0 = e & 63;                                       \
      int a = (y + 1) * STRD + x0 + 1;                                   \
      float4 v0 = hi ? pre[(J) + 1][k] : pre[(J)][k];                    \
      float4 v1 = hi ? pre[(J) + 2][k] : pre[(J) + 1][k];                \
      smb[a] = fmaf(wl, v0.x, wh * v1.x);                                \
      smb[a + 1] = fmaf(wl, v0.y, wh * v1.y);                            \
      smb[a + 2] = fmaf(wl, v0.z, wh * v1.z);                            \
      smb[a + 3] = fmaf(wl, v0.w, wh * v1.w);                            \
    }                                                                    \
  } while (0)

  // bilinear sampler for one plane (256 threads, t in 0..255)
  const float dgx = 2.0f / 63.0f;
  const int w0 = (t & 15) << 2;
  const int h0 = t >> 4;
  const float gx0 = w0 * dgx - 1.0f;
  auto sample_plane = [&](int plane) {
    const float sc = prm[plane][0];
    const float co = prm[plane][1];
    const float si = prm[plane][2];
    const float tt0 = prm[plane][3];
    const float tt1 = prm[plane][4];
    const float* smA = sm + plane * SLICE3;
    float* outp = out + (((size_t)(b << 8) + dbase + plane) << 12);

    const float co32 = co * sc * 32.0f;
    const float si32 = si * sc * 32.0f;
    const float stx = co32 * dgx;
    const float sty = si32 * dgx;
    const float ixw = fmaf(co32, gx0, fmaf(tt0, 32.0f, 31.5f));
    const float iyw = fmaf(si32, gx0, fmaf(tt1, 32.0f, 31.5f));

#pragma unroll
    for (int j = 0; j < 4; ++j) {
      int h = (j << 4) + h0;
      float gy = h * dgx - 1.0f;
      float ix = fmaf(-si32, gy, ixw);
      float iy = fmaf(co32, gy, iyw);
      float rr[4];
#pragma unroll
      for (int q = 0; q < 4; ++q) {
        float x0f = floorf(ix), y0f = floorf(iy);
        float wx = ix - x0f, wy = iy - y0f;
        int xi = (int)x0f, yi = (int)y0f;
        int bx = min(max(xi, -1), 64);  // v_med3_i32
        int by = min(max(yi, -1), 64);
        float wxe = (bx == xi) ? wx : 0.0f;
        float wye = (by == yi) ? wy : 0.0f;
        float w11 = wye * wxe;
        float w10 = wye - w11;
        float w01 = wxe - w11;
        float w00 = (1.0f - wye) - w01;
        int base = (by + 1) * STRD + bx + 1;
        rr[q] = fmaf(smA[base], w00,
                fmaf(smA[base + 1], w01,
                fmaf(smA[base + STRD], w10, smA[base + STRD + 1] * w11)));
        ix += stx;
        iy += sty;
      }
      f4 res;
      res.x = rr[0]; res.y = rr[1]; res.z = rr[2]; res.w = rr[3];
      __builtin_nontemporal_store(res, (f4*)outp + (j << 8) + t);
    }
  };

  // ================= phase 0 =================
  if (tid >= 256) {
    // loader: issue up to 6 slice loads (drain under GEMV / later phases)
    const float4* fmb = (const float4*)(fm + ((size_t)b << 20));
#pragma unroll
    for (int s = 0; s < 6; ++s) {
      int z = zbase + s;
      bool need = (s < 5) || !fast;       // block-uniform
      if (need && (unsigned)z < 256u) {   // block-uniform
        const float4* src = fmb + ((size_t)z << 10);
#pragma unroll
        for (int k = 0; k < 4; ++k) pre[s][k] = src[(k << 8) + t];
      } else {
#pragma unroll
        for (int k = 0; k < 4; ++k) pre[s][k] = make_float4(0.f, 0.f, 0.f, 0.f);
      }
    }
  } else {
    // compute waves: zero guard rings for all 4 slices
#pragma unroll
    for (int ss = 0; ss < 4; ++ss) {
      float* smb = sm + ss * SLICE3;
      if (t < STRD) {
        smb[t] = 0.0f;
        smb[65 * STRD + t] = 0.0f;
        smb[66 * STRD + t] = 0.0f;
      }
      int r = 1 + (t >> 2);
      int q = t & 3;
      int c = q ? (64 + q) : 0;
      smb[r * STRD + c] = 0.0f;
    }
    // issue heads' W/bias loads early (drain under GEMV)
    ws4 = *(const float4*)(W_s + (t << 8) + dbase);
    wr4 = *(const float4*)(W_r + (t << 8) + dbase);
    wt0 = *(const float4*)(W_t + (t << 9) + (dbase << 1));
    wt1 = *(const float4*)(W_t + (t << 9) + (dbase << 1) + 4);
    bcv = b_c[t];
    if (tid < 16) {
      int k = tid, g = k >> 3, j = k & 7, pl = j & 1;
      int dsel = dbase + ((g << 1) | pl), typ = j >> 1;
      bias16 = (typ == 0) ? b_s[dsel]
             : (typ == 1) ? b_r[dsel]
             : (typ == 2) ? b_t[2 * dsel] : b_t[2 * dsel + 1];
    }
    // GEMV p = relu(pc @ W_c + b_c): split-K over waves 0-3 (k=64 each)
    const int wv = t >> 6, ln = t & 63;
    const float* pcb = para_code + (b << 8);
    float pcv = pcb[(wv << 6) | ln];
    float4 a4 = make_float4(0.f, 0.f, 0.f, 0.f);
#pragma unroll
    for (int kk = 0; kk < 64; ++kk) {
      float pk = __int_as_float(
          __builtin_amdgcn_readlane(__float_as_int(pcv), kk));
      const float4* Wrow = (const float4*)(W_c + (((wv << 6) + kk) << 8));
      float4 w4 = Wrow[ln];
      a4.x = fmaf(pk, w4.x, a4.x);
      a4.y = fmaf(pk, w4.y, a4.y);
      a4.z = fmaf(pk, w4.z, a4.z);
      a4.w = fmaf(pk, w4.w, a4.w);
    }
    ((f4*)&redp[wv][0])[ln] = (f4){a4.x, a4.y, a4.z, a4.w};
  }
  __syncthreads();  // B0: redp + guard rings visible

  // ================= phase 1 =================
  if (tid >= 256) {
    if (fast) {
      STAGE(0); STAGE(1);          // needs slices 0-2 only (48 KB drained)
    } else {
      STAGE(0); STAGE(1); STAGE(2); STAGE(3);  // slow path: stage everything
    }
  } else {
    // heads part1: 16 dots, bit-identical association to the 2-group version
    float pk = fmaxf(redp[0][t] + redp[1][t] + redp[2][t] + redp[3][t] + bcv,
                     0.0f);
    float v[16];
    v[0] = pk * ws4.x;  v[1] = pk * ws4.y;   // s  planes 0,1
    v[2] = pk * wr4.x;  v[3] = pk * wr4.y;   // r  planes 0,1
    v[4] = pk * wt0.x;  v[5] = pk * wt0.z;   // t0 planes 0,1
    v[6] = pk * wt0.y;  v[7] = pk * wt0.w;   // t1 planes 0,1
    v[8] = pk * ws4.z;  v[9] = pk * ws4.w;   // s  planes 2,3
    v[10] = pk * wr4.z; v[11] = pk * wr4.w;  // r  planes 2,3
    v[12] = pk * wt1.x; v[13] = pk * wt1.z;  // t0 planes 2,3
    v[14] = pk * wt1.y; v[15] = pk * wt1.w;  // t1 planes 2,3
#pragma unroll
    for (int k = 0; k < 16; ++k) {
#pragma unroll
      for (int off = 32; off > 0; off >>= 1) v[k] += __shfl_xor(v[k], off);
    }
    const int wv = t >> 6;
    if ((t & 63) == 0) {
#pragma unroll
      for (int k4 = 0; k4 < 4; ++k4) {
        f4 r4;
        r4.x = v[k4 * 4]; r4.y = v[k4 * 4 + 1];
        r4.z = v[k4 * 4 + 2]; r4.w = v[k4 * 4 + 3];
        *(f4*)&red[wv][k4 << 2] = r4;
      }
    }
  }
  __syncthreads();  // B1: red + planes 0,1 visible

  // ================= part2: finalize 16 head outputs =================
  if (tid < 16) {
    int k = tid;
    float vsum = red[0][k] + red[1][k] + red[2][k] + red[3][k] + bias16;
    int g = k >> 3, j = k & 7;
    int pl = j & 1;
    int plane = (g << 1) | pl;
    int typ = j >> 1;  // 0:scale 1:rot 2:t0 3:t1
    if (typ == 0) {
      prm[plane][0] = 2.0f / (1.0f + expf(-vsum));
    } else if (typ == 1) {
      float ang = tanhf(vsum) * PI_F;
      prm[plane][1] = cosf(ang);
      prm[plane][2] = sinf(ang);
    } else if (typ == 2) {
      prm[plane][3] = tanhf(vsum);
    } else {
      prm[plane][4] = tanhf(vsum);
    }
  }
  __syncthreads();  // B2: prm visible

  // ================= phase A: planes 0,1 (+ stage 2,3 behind) =================
  if (tid >= 256) {
    sample_plane(1);
    if (fast) {
      STAGE(2); STAGE(3);  // slices 3,4 drained during plane-1 sampling
    }
  } else {
    sample_plane(0);
  }
  __syncthreads();  // B3: planes 2,3 visible

  // ================= phase B: planes 2,3 =================
  if (tid >= 256) {
    sample_plane(3);
  } else {
    sample_plane(2);
  }
#undef STAGE
}

extern "C" void kernel_launch(void* const* d_in, const int* in_sizes, int n_in,
                              void* d_out, int out_size, void* d_ws, size_t ws_size,
                              hipStream_t stream) {
  const float* fm        = (const float*)d_in[0];  // (4,256,64,64)
  const float* para_code = (const float*)d_in[1];  // (4,256)
  const float* W_c       = (const float*)d_in[2];  // (256,256)
  const float* b_c       = (const float*)d_in[3];  // (256,)
  const float* W_s       = (const float*)d_in[4];  // (256,256)
  const float* b_s       = (const float*)d_in[5];  // (256,)
  const float* W_r       = (const float*)d_in[6];  // (256,256)
  const float* b_r       = (const float*)d_in[7];  // (256,)
  const float* W_t       = (const float*)d_in[8];  // (256,512)
  const float* b_t       = (const float*)d_in[9];  // (512,)
  float* out = (float*)d_out;

  adaat_fused_kernel<<<256, 512, 0, stream>>>(
      fm, para_code, W_c, b_c, W_s, b_s, W_r, b_r, W_t, b_t, out);
}